// Round 12
// baseline (315.560 us; speedup 1.0000x reference)
//
#include <hip/hip_runtime.h>

#define S_LEN 2048
#define HID   2048
#define NQH   32
#define NKV   8
#define HD    64

#define BM 128
#define BN 128
#define BK 32

typedef __bf16 bf16x8 __attribute__((ext_vector_type(8)));
typedef __bf16 bf16x4 __attribute__((ext_vector_type(4)));
typedef float  f32x4  __attribute__((ext_vector_type(4)));

#define MFMA16(a, b, c) __builtin_amdgcn_mfma_f32_16x16x32_bf16(a, b, c, 0, 0, 0)

__device__ __forceinline__ void async_copy16(const void* g, void* l) {
  __builtin_amdgcn_global_load_lds(
      (const __attribute__((address_space(1))) unsigned int*)g,
      (__attribute__((address_space(3))) unsigned int*)l, 16, 0, 0);
}

__device__ __forceinline__ unsigned cvtpk_bf16(float lo, float hi) {
  unsigned r;
  asm("v_cvt_pk_bf16_f32 %0, %1, %2" : "=v"(r) : "v"(lo), "v"(hi));
  return r;
}

// raw v_exp_f32 / v_rcp_f32: skip the denormal-guard libm expansion.
__device__ __forceinline__ float exp2_raw(float x) {
  float r;
  asm("v_exp_f32 %0, %1" : "=v"(r) : "v"(x));
  return r;
}
__device__ __forceinline__ float rcp_raw(float x) {
  float r;
  asm("v_rcp_f32 %0, %1" : "=v"(r) : "v"(x));
  return r;
}

// ---------------- fused f32 -> bf16 cast of x + all weights ----------------
__global__ void cast_all_k(const float* __restrict__ x,  const float* __restrict__ wq,
                           const float* __restrict__ wk, const float* __restrict__ wv,
                           const float* __restrict__ wo,
                           __bf16* __restrict__ xb,  __bf16* __restrict__ wqb,
                           __bf16* __restrict__ wkb, __bf16* __restrict__ wvb,
                           __bf16* __restrict__ wob) {
  int bid = blockIdx.x;
  const float* in; __bf16* out; int base;
  if (bid < 8192)       { in = x;  out = xb;  base = bid; }
  else if (bid < 12288) { in = wq; out = wqb; base = bid - 8192; }
  else if (bid < 13312) { in = wk; out = wkb; base = bid - 12288; }
  else if (bid < 14336) { in = wv; out = wvb; base = bid - 13312; }
  else                  { in = wo; out = wob; base = bid - 14336; }
  int i = (base * 256 + threadIdx.x) * 4;
  float4 v = *(const float4*)(in + i);
  bf16x4 o;
  o[0] = (__bf16)v.x; o[1] = (__bf16)v.y; o[2] = (__bf16)v.z; o[3] = (__bf16)v.w;
  *(bf16x4*)(out + i) = o;
}

// ---------------- 256x256 BK=32 GEMM core, 8 waves (2Mx4N), 3-stage counted-vmcnt ----------------
// Scale-up of the proven 128x128 skeleton: per-wave output 128x64 (8x4 frags) ->
// 32 MFMA per 12 frag-reads (vs 16/8) -> LDS-read time (~1280cyc/CU/tile) now
// balances MFMA (~1242cyc) instead of exceeding it 1.5x. LDS 3x32KB=96KB ->
// 1 block/CU; 3-stage + vmcnt(4) pipeline substitutes for block-level overlap.
// Swizzle algebra carries over verbatim: all row offsets are multiples of 4, so
// k(row)=(row>>1)&3 reduces to (l15>>1)&3 on reads and (tid>>3)&3 on staging.
__device__ __forceinline__ void gemm_pipe256(const __bf16* __restrict__ A,
                                             const __bf16* __restrict__ B,
                                             int m0, int n0, int K,
                                             __bf16 (&As)[3][256][32],
                                             __bf16 (&Bs)[3][256][32],
                                             f32x4 (&acc)[8][4]) {
  const int tid = threadIdx.x, wave = tid >> 6, lane = tid & 63;
  const int l15 = lane & 15, quad = lane >> 4;
  const int wr = wave >> 2, wc = wave & 3;

  // staging: 512 thr x 16B = 8KB = 128 rows/issue; 2 issues per matrix per tile.
  const int srow   = tid >> 2;                       // 0..127
  const int schunk = (tid & 3) ^ ((tid >> 3) & 3);   // source pre-swizzled (rule #21)
  const __bf16* ga = A + (size_t)(m0 + srow) * K + schunk * 8;
  const __bf16* gb = B + (size_t)(n0 + srow) * K + schunk * 8;

  const int co = (quad ^ ((l15 >> 1) & 3)) * 8;
  const int NT = K / 32;

#define STAGE2(st, kt) do {                                                 \
    async_copy16(ga + (kt),                   &As[st][wave * 16][0]);       \
    async_copy16(ga + (kt) + (size_t)128 * K, &As[st][128 + wave * 16][0]); \
    async_copy16(gb + (kt),                   &Bs[st][wave * 16][0]);       \
    async_copy16(gb + (kt) + (size_t)128 * K, &Bs[st][128 + wave * 16][0]); \
  } while (0)

  STAGE2(0, 0);
  STAGE2(1, 32);

  int s = 0;
#pragma unroll 3
  for (int t = 0; t < NT; t++) {
    // vmcnt(4): tile t's 4 issues (from t-2) certified; tile t+1's 4 stay in flight.
    if (t + 1 < NT) asm volatile("s_waitcnt vmcnt(4)" ::: "memory");
    else            asm volatile("s_waitcnt vmcnt(0)" ::: "memory");
    __builtin_amdgcn_s_barrier();
    asm volatile("" ::: "memory");

    if (t + 2 < NT) {
      int s2 = s + 2; if (s2 >= 3) s2 -= 3;
      STAGE2(s2, (t + 2) * 32);
    }

    const __bf16* a0 = &As[s][wr * 128][0];
    const __bf16* b0 = &Bs[s][wc * 64][0];
    bf16x8 bfr[4];
#pragma unroll
    for (int nt = 0; nt < 4; nt++)
      bfr[nt] = *(const bf16x8*)(b0 + (nt * 16 + l15) * 32 + co);

    // two mt-halves to cap register liveness (af[4] live at a time)
#pragma unroll
    for (int mh = 0; mh < 2; mh++) {
      bf16x8 af[4];
#pragma unroll
      for (int mt = 0; mt < 4; mt++)
        af[mt] = *(const bf16x8*)(a0 + ((mh * 4 + mt) * 16 + l15) * 32 + co);
      __builtin_amdgcn_s_setprio(1);
#pragma unroll
      for (int mt = 0; mt < 4; mt++)
#pragma unroll
        for (int nt = 0; nt < 4; nt++)
          acc[mh * 4 + mt][nt] = MFMA16(af[mt], bfr[nt], acc[mh * 4 + mt][nt]);
      __builtin_amdgcn_s_setprio(0);
    }

    s = s + 1; if (s >= 3) s -= 3;
  }
#undef STAGE2
}

// fused QKV projection + RoPE(K) + V transpose. grid (16, 12), 512 thr.
__global__ __launch_bounds__(512, 2) void gemm_qkv_k(const __bf16* __restrict__ xb,
    const __bf16* __restrict__ wqb, const __bf16* __restrict__ wkb, const __bf16* __restrict__ wvb,
    const float* __restrict__ bq, const float* __restrict__ bk, const float* __restrict__ bv,
    const float* __restrict__ fr,
    __bf16* __restrict__ Qb, __bf16* __restrict__ Kb, __bf16* __restrict__ Vt) {
  __shared__ __align__(16) __bf16 As[3][256][32];
  __shared__ __align__(16) __bf16 Bs[3][256][32];
  const int by = blockIdx.y;
  const int m0 = blockIdx.x * 256;
  const __bf16* B; const float* bias; int n0;
  int mode;  // 0 = plain Q, 1 = ropeK, 2 = vtrans
  if (by < 8)       { B = wqb; bias = bq; n0 = by * 256;        mode = 0; }
  else if (by < 10) { B = wkb; bias = bk; n0 = (by - 8) * 256;  mode = 1; }
  else              { B = wvb; bias = bv; n0 = (by - 10) * 256; mode = 2; }

  f32x4 acc[8][4] = {};
  gemm_pipe256(xb, B, m0, n0, HID, As, Bs, acc);

  const int tid = threadIdx.x, wave = tid >> 6, lane = tid & 63;
  const int l15 = lane & 15, quad = lane >> 4;
  const int wr = wave >> 2, wc = wave & 3;

  if (mode == 2) {
#pragma unroll
    for (int nt = 0; nt < 4; nt++) {
      int col = n0 + wc * 64 + nt * 16 + l15;       // 0..511
      int g = col >> 6, d = col & 63;
      float bv2 = bias[col];
#pragma unroll
      for (int mt = 0; mt < 8; mt++) {
        int row = m0 + wr * 128 + mt * 16 + quad * 4;
        int b = row >> 11, sI = row & 2047;
        bf16x4 o;
#pragma unroll
        for (int r = 0; r < 4; r++) o[r] = (__bf16)(acc[mt][nt][r] + bv2);
        *(bf16x4*)(Vt + (((size_t)(b * NKV + g) * HD + d)) * S_LEN + sI) = o;
      }
    }
  } else if (mode == 0) {
#pragma unroll
    for (int nt = 0; nt < 4; nt++) {
      int col = n0 + wc * 64 + nt * 16 + l15;
      float bv2 = bias[col];
#pragma unroll
      for (int mt = 0; mt < 8; mt++) {
        int row = m0 + wr * 128 + mt * 16 + quad * 4;
#pragma unroll
        for (int r = 0; r < 4; r++)
          Qb[(size_t)(row + r) * HID + col] = (__bf16)(acc[mt][nt][r] + bv2);
      }
    }
  } else {
    const int dpar = l15 & 1;
#pragma unroll
    for (int nt = 0; nt < 4; nt++) {
      int col = n0 + wc * 64 + nt * 16 + l15;       // 0..511
      int d = col & 63;
      float bv2 = bias[col];
#pragma unroll
      for (int mt = 0; mt < 8; mt++) {
        int row = m0 + wr * 128 + mt * 16 + quad * 4;
        int sI = row & 2047;
#pragma unroll
        for (int r = 0; r < 4; r++) {
          float v = acc[mt][nt][r] + bv2;
          float p = __shfl_xor(v, 1, 64);
          float f = fr[(size_t)(sI + r) * HD + d];
          float fp = __shfl_xor(f, 1, 64);
          float o = dpar ? (p * f + v * fp) : (v * f - p * fp);
          Kb[(size_t)(row + r) * 512 + col] = (__bf16)o;
        }
      }
    }
  }
}

// ---------------- 128x128 BK=32 GEMM core (proven R7/R11) -- used by gemm_out ----------------
__device__ __forceinline__ void gemm_pipe(const __bf16* __restrict__ A,
                                          const __bf16* __restrict__ B,
                                          int m0, int n0, int K,
                                          __bf16 (&As)[3][BM][BK],
                                          __bf16 (&Bs)[3][BN][BK],
                                          f32x4 (&acc)[4][4]) {
  const int tid = threadIdx.x, wave = tid >> 6, lane = tid & 63;
  const int l15 = lane & 15, quad = lane >> 4;
  const int wr = wave >> 1, wc = wave & 1;

  const int srow   = tid >> 2;
  const int schunk = (tid & 3) ^ ((tid >> 3) & 3);
  const __bf16* ga = A + (size_t)(m0 + srow) * K + schunk * 8;
  const __bf16* gb = B + (size_t)(n0 + srow) * K + schunk * 8;

  const int co = (quad ^ ((l15 >> 1) & 3)) * 8;

  const int NT = K / BK;

#define STAGE(st, kt) do {                                              \
    async_copy16(ga + (kt),                  &As[st][wave * 16][0]);    \
    async_copy16(ga + (kt) + (size_t)64 * K, &As[st][64 + wave * 16][0]); \
    async_copy16(gb + (kt),                  &Bs[st][wave * 16][0]);    \
    async_copy16(gb + (kt) + (size_t)64 * K, &Bs[st][64 + wave * 16][0]); \
  } while (0)

  STAGE(0, 0);
  STAGE(1, BK);

  int s = 0;
#pragma unroll 3
  for (int t = 0; t < NT; t++) {
    if (t + 1 < NT) asm volatile("s_waitcnt vmcnt(4)" ::: "memory");
    else            asm volatile("s_waitcnt vmcnt(0)" ::: "memory");
    __builtin_amdgcn_s_barrier();
    asm volatile("" ::: "memory");

    if (t + 2 < NT) {
      int s2 = s + 2; if (s2 >= 3) s2 -= 3;
      STAGE(s2, (t + 2) * BK);
    }

    const __bf16* a0 = &As[s][wr * 64][0];
    const __bf16* b0 = &Bs[s][wc * 64][0];
    bf16x8 af[4], bfr[4];
#pragma unroll
    for (int mt = 0; mt < 4; mt++)
      af[mt] = *(const bf16x8*)(a0 + (mt * 16 + l15) * BK + co);
#pragma unroll
    for (int nt = 0; nt < 4; nt++)
      bfr[nt] = *(const bf16x8*)(b0 + (nt * 16 + l15) * BK + co);

    __builtin_amdgcn_s_setprio(1);
#pragma unroll
    for (int mt = 0; mt < 4; mt++)
#pragma unroll
      for (int nt = 0; nt < 4; nt++)
        acc[mt][nt] = MFMA16(af[mt], bfr[nt], acc[mt][nt]);
    __builtin_amdgcn_s_setprio(0);

    s = s + 1; if (s >= 3) s -= 3;
  }
#undef STAGE
}

// output projection: grid (32, 16) = 512 blocks
__global__ __launch_bounds__(256, 3) void gemm_out_k(const __bf16* __restrict__ A,
    const __bf16* __restrict__ Bw, const float* __restrict__ bias, float* __restrict__ C) {
  __shared__ __align__(16) __bf16 As[3][BM][BK];
  __shared__ __align__(16) __bf16 Bs[3][BN][BK];
  const int m0 = blockIdx.x * BM, n0 = blockIdx.y * BN;
  f32x4 acc[4][4] = {};
  gemm_pipe(A, Bw, m0, n0, HID, As, Bs, acc);
  const int tid = threadIdx.x, wave = tid >> 6, lane = tid & 63;
  const int l15 = lane & 15, quad = lane >> 4;
  const int wr = wave >> 1, wc = wave & 1;
#pragma unroll
  for (int nt = 0; nt < 4; nt++) {
    int col = n0 + wc * 64 + nt * 16 + l15;
    float bv = bias[col];
#pragma unroll
    for (int mt = 0; mt < 4; mt++) {
      int row = m0 + wr * 64 + mt * 16 + quad * 4;
#pragma unroll
      for (int r = 0; r < 4; r++)
        C[(size_t)(row + r) * HID + col] = acc[mt][nt][r] + bv;
    }
  }
}

// RoPE a bf16x8 (pairs 2j,2j+1 adjacent) with contiguous f32 freqs, fused scale.
__device__ __forceinline__ void rope8(bf16x8& q, const float* f, float sc) {
  float4 fa = *(const float4*)f;
  float4 fb = *(const float4*)(f + 4);
  float e, o;
  e = (float)q[0]; o = (float)q[1];
  q[0] = (__bf16)((e * fa.x - o * fa.y) * sc);
  q[1] = (__bf16)((e * fa.y + o * fa.x) * sc);
  e = (float)q[2]; o = (float)q[3];
  q[2] = (__bf16)((e * fa.z - o * fa.w) * sc);
  q[3] = (__bf16)((e * fa.w + o * fa.z) * sc);
  e = (float)q[4]; o = (float)q[5];
  q[4] = (__bf16)((e * fb.x - o * fb.y) * sc);
  q[5] = (__bf16)((e * fb.y + o * fb.x) * sc);
  e = (float)q[6]; o = (float)q[7];
  q[6] = (__bf16)((e * fb.z - o * fb.w) * sc);
  q[7] = (__bf16)((e * fb.w + o * fb.z) * sc);
}

// ---------------- Flash attention v10 (known-good, round-9/11 config) ----------------
__global__ __launch_bounds__(256, 2) void flash_k(const __bf16* __restrict__ Q,
                                                  const __bf16* __restrict__ K,
                                                  const __bf16* __restrict__ Vt,
                                                  const float* __restrict__ fr,
                                                  __bf16* __restrict__ O) {
  __shared__ __align__(64) __bf16 Ksm[2][64][64];    // [buf][kv][d] swizzled (key=row&7)
  __shared__ __align__(64) __bf16 Vsm[2][64][64];    // [buf][d][kv] swizzled
  const int tid = threadIdx.x;
  const int wave = tid >> 6, lane = tid & 63;
  const int l15 = lane & 15, quad = lane >> 4;
  const int bh = blockIdx.x;
  const int b = bh >> 5, h = bh & 31, g = h >> 2;

  const int srow = tid >> 2, sc = (tid & 3) * 16;
  const int r7 = srow & 7;
  const int w0 = (((sc >> 3))     ^ r7) * 8;
  const int w1 = (((sc >> 3) + 1) ^ r7) * 8;

  const char* kbp = (const char*)&Ksm[0][0][0];
  const char* vbp = (const char*)&Vsm[0][0][0];

  const int x7  = l15 & 7;
  const int sig = 8 * ((l15 >> 2) & 1) + 4 * (l15 >> 3) + (l15 & 3);
  const int s7  = sig & 7;
  int krK[2], krV[2];
#pragma unroll
  for (int ks = 0; ks < 2; ks++) {
    krK[ks] = sig * 128 + (((ks * 4 + quad) ^ s7) * 16);
    krV[ks] = l15 * 128 + (((ks * 4 + quad) ^ x7) * 16);
  }
  const int kvb = 8 * (quad & 1) + 4 * (quad >> 1);

  bf16x8 ones;
#pragma unroll
  for (int j = 0; j < 8; j++) ones[j] = (__bf16)1.0f;

  const __bf16* kbase = K + ((size_t)b * S_LEN + srow) * (NKV * HD) + g * HD + sc;
  const __bf16* vbase = Vt + (((size_t)b * NKV + g) * HD + srow) * S_LEN + sc;
  const float QSC = 0.125f * 1.44269504f;   // 1/sqrt(64) * log2(e)
  const int KSTEP = 64 * NKV * HD;

#pragma unroll 1
  for (int half = 0; half < 2; half++) {
    const int qt = half ? (15 - (int)blockIdx.y) : (int)blockIdx.y;
    const int NT = 2 * qt + 2;                 // kv tiles for this q-tile
    const int wq0 = qt * 128 + wave * 16;      // group A rows; group B = +64

    const __bf16* qpA = Q + ((size_t)(b * S_LEN + wq0 + l15)) * HID + h * HD + quad * 8;
    const __bf16* qpB = qpA + (size_t)64 * HID;
    bf16x8 qfA0 = *(const bf16x8*)qpA;
    bf16x8 qfA1 = *(const bf16x8*)(qpA + 32);
    bf16x8 qfB0 = *(const bf16x8*)qpB;
    bf16x8 qfB1 = *(const bf16x8*)(qpB + 32);
    const float* fqA = fr + (size_t)(wq0 + l15) * HD + quad * 8;
    const float* fqB = fqA + (size_t)64 * HD;
    rope8(qfA0, fqA, QSC);
    rope8(qfA1, fqA + 32, QSC);
    rope8(qfB0, fqB, QSC);
    rope8(qfB1, fqB + 32, QSC);

    f32x4 accA[4] = {}, accB[4] = {};
    f32x4 accsA = {}, accsB = {};

    const __bf16* kp = kbase;
    const __bf16* vp = vbase;
    uint4 k0 = *(const uint4*)kp, k1 = *(const uint4*)(kp + 8);
    uint4 v0 = *(const uint4*)vp, v1 = *(const uint4*)(vp + 8);
    *(uint4*)&Ksm[0][srow][w0] = k0;
    *(uint4*)&Ksm[0][srow][w1] = k1;
    *(uint4*)&Vsm[0][srow][w0] = v0;
    *(uint4*)&Vsm[0][srow][w1] = v1;
    // NT >= 2 always: prefetch tile 1
    kp += KSTEP;  vp += 64;
    k0 = *(const uint4*)kp; k1 = *(const uint4*)(kp + 8);
    v0 = *(const uint4*)vp; v1 = *(const uint4*)(vp + 8);
    __syncthreads();

#pragma unroll 1
    for (int t = 0; t < NT; t++) {
      const int cur = t & 1;
      const int kv0 = t * 64;

      if (t + 1 < NT) {
        *(uint4*)&Ksm[cur ^ 1][srow][w0] = k0;
        *(uint4*)&Ksm[cur ^ 1][srow][w1] = k1;
        *(uint4*)&Vsm[cur ^ 1][srow][w0] = v0;
        *(uint4*)&Vsm[cur ^ 1][srow][w1] = v1;
        if (t + 2 < NT) {
          kp += KSTEP;  vp += 64;
          k0 = *(const uint4*)kp; k1 = *(const uint4*)(kp + 8);
          v0 = *(const uint4*)vp; v1 = *(const uint4*)(vp + 8);
        }
      }

      const bool actA = (kv0 <= wq0 + 15);   // group A not fully masked (uniform/wave)
      const int cb = cur * 8192;

      bf16x8 kf[2][4];
#pragma unroll
      for (int ks = 0; ks < 2; ks++)
#pragma unroll
        for (int nt = 0; nt < 4; nt++)
          kf[ks][nt] = *(const bf16x8*)(kbp + cb + krK[ks] + nt * 2048);

      // ---- group B scores (always active; B q-rows = wq0+64..) ----
      unsigned WB[4][2];
      {
        f32x4 sacc[4] = {};
        __builtin_amdgcn_s_setprio(1);
#pragma unroll
        for (int nt = 0; nt < 4; nt++) {
          sacc[nt] = MFMA16(kf[0][nt], qfB0, sacc[nt]);
          sacc[nt] = MFMA16(kf[1][nt], qfB1, sacc[nt]);
        }
        __builtin_amdgcn_s_setprio(0);
        const int wq0B = wq0 + 64;
        const bool domask = (kv0 + 63 > wq0B);
        const int md = wq0B + l15 - kv0 - kvb;
#pragma unroll
        for (int nt = 0; nt < 4; nt++) {
          f32x4 pv;
#pragma unroll
          for (int r = 0; r < 4; r++) pv[r] = exp2_raw(sacc[nt][r]);
          if (domask) {
#pragma unroll
            for (int r = 0; r < 4; r++)
              if (nt * 16 + r > md) pv[r] = 0.f;
          }
          WB[nt][0] = cvtpk_bf16(pv[0], pv[1]);
          WB[nt][1] = cvtpk_bf16(pv[2], pv[3]);
        }
      }
      // ---- group A scores ----
      unsigned WA[4][2];
      if (actA) {
        f32x4 sacc[4] = {};
        __builtin_amdgcn_s_setprio(1);
#pragma unroll
        for (int nt = 0; nt < 4; nt++) {
          sacc[nt] = MFMA16(kf[0][nt], qfA0, sacc[nt]);
          sacc[nt] = MFMA16(kf[1][nt], qfA1, sacc[nt]);
        }
        __builtin_amdgcn_s_setprio(0);
        const bool domask = (kv0 + 63 > wq0);
        const int md = wq0 + l15 - kv0 - kvb;
#pragma unroll
        for (int nt = 0; nt < 4; nt++) {
          f32x4 pv;
#pragma unroll
          for (int r = 0; r < 4; r++) pv[r] = exp2_raw(sacc[nt][r]);
          if (domask) {
#pragma unroll
            for (int r = 0; r < 4; r++)
              if (nt * 16 + r > md) pv[r] = 0.f;
          }
          WA[nt][0] = cvtpk_bf16(pv[0], pv[1]);
          WA[nt][1] = cvtpk_bf16(pv[2], pv[3]);
        }
      }

      // ---- PV for both groups; vf read once ----
#pragma unroll
      for (int ks = 0; ks < 2; ks++) {
        bf16x8 vf[4];
#pragma unroll
        for (int nt = 0; nt < 4; nt++)
          vf[nt] = *(const bf16x8*)(vbp + cb + krV[ks] + nt * 2048);

        {
          unsigned a0 = WB[2 * ks][0], b0 = WB[2 * ks + 1][0];
          unsigned a1 = WB[2 * ks][1], b1 = WB[2 * ks + 1][1];
          asm("v_permlane32_swap_b32 %0, %1" : "+v"(a0), "+v"(b0));
          asm("v_permlane32_swap_b32 %0, %1" : "+v"(a1), "+v"(b1));
          union { unsigned u[4]; bf16x8 v; } pk;
          pk.u[0] = a0; pk.u[1] = a1; pk.u[2] = b0; pk.u[3] = b1;
          bf16x8 pf = pk.v;
          __builtin_amdgcn_s_setprio(1);
          accsB = MFMA16(pf, ones, accsB);
#pragma unroll
          for (int nt = 0; nt < 4; nt++)
            accB[nt] = MFMA16(pf, vf[nt], accB[nt]);
          __builtin_amdgcn_s_setprio(0);
        }
        if (actA) {
          unsigned a0 = WA[2 * ks][0], b0 = WA[2 * ks + 1][0];
          unsigned a1 = WA[2 * ks][1], b1 = WA[2 * ks + 1][1];
          asm("v_permlane32_swap_b32 %0, %1" : "+v"(a0), "+v"(b0));
          asm("v_permlane32_swap_b32 %0, %1" : "+v"(a1), "+v"(b1));
          union { unsigned u[4]; bf16x8 v; } pk;
          pk.u[0] = a0; pk.u[1] = a1; pk.u[2] = b0; pk.u[3] = b1;
          bf16x8 pf = pk.v;
          __builtin_amdgcn_s_setprio(1);
          accsA = MFMA16(pf, ones, accsA);
#pragma unroll
          for (int nt = 0; nt < 4; nt++)
            accA[nt] = MFMA16(pf, vf[nt], accA[nt]);
          __builtin_amdgcn_s_setprio(0);
        }
      }

      __syncthreads();
    }

    // epilogue for both groups (rows quad*4+r; group B rows +64)
    __bf16* opA = O + ((size_t)(b * S_LEN + wq0 + quad * 4)) * HID + h * HD;
    __bf16* opB = opA + (size_t)64 * HID;
    float invA[4], invB[4];
#pragma unroll
    for (int r = 0; r < 4; r++) { invA[r] = rcp_raw(accsA[r]); invB[r] = rcp_raw(accsB[r]); }
#pragma unroll
    for (int nt = 0; nt < 4; nt++)
#pragma unroll
      for (int r = 0; r < 4; r++) {
        opA[(size_t)r * HID + nt * 16 + l15] = (__bf16)(accA[nt][r] * invA[r]);
        opB[(size_t)r * HID + nt * 16 + l15] = (__bf16)(accB[nt][r] * invB[r]);
      }
  }
}

extern "C" void kernel_launch(void* const* d_in, const int* in_sizes, int n_in,
                              void* d_out, int out_size, void* d_ws, size_t ws_size,
                              hipStream_t stream) {
  (void)in_sizes; (void)n_in; (void)out_size; (void)ws_size;
  const float* x  = (const float*)d_in[0];
  const float* fr = (const float*)d_in[1];
  const float* wq = (const float*)d_in[3];
  const float* bq = (const float*)d_in[4];
  const float* wk = (const float*)d_in[5];
  const float* bk = (const float*)d_in[6];
  const float* wv = (const float*)d_in[7];
  const float* bv = (const float*)d_in[8];
  const float* wo = (const float*)d_in[9];
  const float* bo = (const float*)d_in[10];
  float* out = (float*)d_out;
  char* ws = (char*)d_ws;

  __bf16* xb  = (__bf16*)(ws);
  __bf16* wqb = (__bf16*)(ws + ((size_t)16 << 20));
  __bf16* wkb = (__bf16*)(ws + ((size_t)24 << 20));
  __bf16* wvb = (__bf16*)(ws + ((size_t)26 << 20));
  __bf16* wob = (__bf16*)(ws + ((size_t)28 << 20));
  __bf16* Qb  = (__bf16*)(ws + ((size_t)36 << 20));
  __bf16* Kb  = (__bf16*)(ws + ((size_t)52 << 20));
  __bf16* Vtb = (__bf16*)(ws + ((size_t)60 << 20));
  __bf16* Ab  = (__bf16*)(ws + ((size_t)64 << 20));

  cast_all_k<<<18432, 256, 0, stream>>>(x, wq, wk, wv, wo, xb, wqb, wkb, wvb, wob);

  gemm_qkv_k<<<dim3(16, 12), 512, 0, stream>>>(xb, wqb, wkb, wvb, bq, bk, bv, fr, Qb, Kb, Vtb);

  flash_k<<<dim3(64, 8), 256, 0, stream>>>(Qb, Kb, Vtb, fr, Ab);

  gemm_out_k<<<dim3(32, 16), 256, 0, stream>>>(Ab, wob, bo, out);
}